// Round 1
// baseline (1047.731 us; speedup 1.0000x reference)
//
#include <hip/hip_runtime.h>
#include <cstdint>
#include <cstddef>

// ---------------------------------------------------------------------------
// PiFormerFFN: out = gelu_q(x @ W1^T) @ W2^T
//   x  [8192, 2048] fp32,  W1 [8192, 2048] fp32,  W2 [2048, 8192] fp32
//   weights are ternary * 2^-e (exact in bf16); compute both GEMMs in bf16
//   MFMA (16x16x32), accumulate fp32.  Activation: q = rint(h/0.1) clipped to
//   int16 range, a = tanh-approx gelu(q*0.1)  (JAX gelu default approximate).
// ---------------------------------------------------------------------------

typedef __bf16 bf16_t;
typedef bf16_t bf16x8 __attribute__((ext_vector_type(8)));
typedef bf16_t bf16x4 __attribute__((ext_vector_type(4)));
typedef float  floatx4 __attribute__((ext_vector_type(4)));

#define AS1 __attribute__((address_space(1)))
#define AS3 __attribute__((address_space(3)))

__device__ __forceinline__ void async_cp16(const void* g, void* l) {
    __builtin_amdgcn_global_load_lds((const AS1 void*)g, (AS3 void*)l, 16, 0, 0);
}

__device__ __forceinline__ float gelu_tanh(float x) {
    const float k0 = 0.7978845608028654f;   // sqrt(2/pi)
    const float k1 = 0.044715f;
    float u = k0 * (x + k1 * x * x * x);
    return 0.5f * x * (1.0f + tanhf(u));
}

// fp32 -> bf16 (RNE), 4 elems/thread
__global__ __launch_bounds__(256)
void cvt_f32_to_bf16(const float4* __restrict__ in, bf16x4* __restrict__ out, int n4)
{
    int i = blockIdx.x * blockDim.x + threadIdx.x;
    if (i >= n4) return;
    float4 v = in[i];
    bf16x4 o;
    o[0] = (bf16_t)v.x; o[1] = (bf16_t)v.y; o[2] = (bf16_t)v.z; o[3] = (bf16_t)v.w;
    out[i] = o;
}

// C[M,N] = A[M,K] * B[N,K]^T   (both inputs K-contiguous; bf16 in, fp32 acc)
// 128x128 block tile, 256 threads = 4 waves in 2x2, each wave 4x4 MFMA tiles.
// BK=32, global_load_lds width-16 staging, 2-barrier K-loop (m97 structure).
template<bool ACT, typename OutT>
__global__ __launch_bounds__(256)
void gemm_bt(const bf16_t* __restrict__ A, const bf16_t* __restrict__ B,
             OutT* __restrict__ C, int M, int N, int K)
{
    __shared__ __align__(16) bf16_t As[128 * 32];   // row-major [128][32], no pad
    __shared__ __align__(16) bf16_t Bs[128 * 32];

    const int tid  = threadIdx.x;
    const int lane = tid & 63;
    const int wave = tid >> 6;
    const int wr = (wave >> 1) * 64;         // wave row offset in tile
    const int wc = (wave & 1) * 64;          // wave col offset in tile
    const int brow = blockIdx.y * 128;
    const int bcol = blockIdx.x * 128;

    const int lane_m = lane & 15;            // MFMA row/col within 16
    const int lane_q = lane >> 4;            // quad 0..3

    floatx4 acc[4][4];
    #pragma unroll
    for (int i = 0; i < 4; ++i)
      #pragma unroll
      for (int j = 0; j < 4; ++j)
        acc[i][j] = (floatx4)0.0f;

    // Staging: 512 chunks of 16B per tile; thread t does chunks t and t+256.
    // chunk c -> tile row c>>2, k-offset (c&3)*8.  LDS offset = c*16 =
    // wave_base + lane*16  (satisfies wave-uniform-base constraint).
    const int c0 = tid, c1 = tid + 256;
    const int r0 = c0 >> 2, o0 = (c0 & 3) * 8;
    const int r1 = c1 >> 2, o1 = (c1 & 3) * 8;

    const bf16_t* Arow0 = A + (size_t)(brow + r0) * K + o0;
    const bf16_t* Arow1 = A + (size_t)(brow + r1) * K + o1;
    const bf16_t* Brow0 = B + (size_t)(bcol + r0) * K + o0;
    const bf16_t* Brow1 = B + (size_t)(bcol + r1) * K + o1;

    for (int kt = 0; kt < K; kt += 32) {
        async_cp16(Arow0 + kt, (char*)As + c0 * 16);
        async_cp16(Arow1 + kt, (char*)As + c1 * 16);
        async_cp16(Brow0 + kt, (char*)Bs + c0 * 16);
        async_cp16(Brow1 + kt, (char*)Bs + c1 * 16);
        __syncthreads();

        // A frag: lane holds A[m=lane_m][k = lane_q*8 .. +8]; B symmetric.
        bf16x8 af[4], bfr[4];
        #pragma unroll
        for (int i = 0; i < 4; ++i) {
            af[i]  = *(const bf16x8*)(As + (wr + i * 16 + lane_m) * 32 + lane_q * 8);
            bfr[i] = *(const bf16x8*)(Bs + (wc + i * 16 + lane_m) * 32 + lane_q * 8);
        }
        #pragma unroll
        for (int mi = 0; mi < 4; ++mi)
          #pragma unroll
          for (int ni = 0; ni < 4; ++ni)
            acc[mi][ni] = __builtin_amdgcn_mfma_f32_16x16x32_bf16(
                af[mi], bfr[ni], acc[mi][ni], 0, 0, 0);
        __syncthreads();
    }

    // Epilogue. C/D layout: col = lane&15, row = (lane>>4)*4 + reg.
    #pragma unroll
    for (int mi = 0; mi < 4; ++mi) {
      #pragma unroll
      for (int ni = 0; ni < 4; ++ni) {
        const int col = bcol + wc + ni * 16 + lane_m;
        #pragma unroll
        for (int r = 0; r < 4; ++r) {
          const int row = brow + wr + mi * 16 + lane_q * 4 + r;
          float h = acc[mi][ni][r];
          if (ACT) {
            float q = rintf(h / 0.1f);            // np.round: half-to-even
            q = fminf(fmaxf(q, -32768.0f), 32767.0f);
            h = gelu_tanh(q * 0.1f);
          }
          C[(size_t)row * N + col] = (OutT)h;
        }
      }
    }
}

extern "C" void kernel_launch(void* const* d_in, const int* in_sizes, int n_in,
                              void* d_out, int out_size, void* d_ws, size_t ws_size,
                              hipStream_t stream)
{
    const int M  = 8192;   // BATCH*SEQ
    const int DM = 2048;   // d_model
    const int DF = 8192;   // d_ff

    const float* x  = (const float*)d_in[0];
    const float* W1 = (const float*)d_in[1];
    const float* W2 = (const float*)d_in[2];
    float* out = (float*)d_out;

    // workspace layout (bf16): xb[M*DM] w1b[DF*DM] w2b[DM*DF] act[M*DF]
    bf16_t* xb  = (bf16_t*)d_ws;
    bf16_t* w1b = xb  + (size_t)M  * DM;
    bf16_t* w2b = w1b + (size_t)DF * DM;
    bf16_t* act = w2b + (size_t)DM * DF;

    {
        int n4 = (M * DM) / 4;
        cvt_f32_to_bf16<<<(n4 + 255) / 256, 256, 0, stream>>>((const float4*)x,  (bf16x4*)xb,  n4);
        n4 = (DF * DM) / 4;
        cvt_f32_to_bf16<<<(n4 + 255) / 256, 256, 0, stream>>>((const float4*)W1, (bf16x4*)w1b, n4);
        n4 = (DM * DF) / 4;
        cvt_f32_to_bf16<<<(n4 + 255) / 256, 256, 0, stream>>>((const float4*)W2, (bf16x4*)w2b, n4);
    }

    // GEMM1 + fused quant/gelu: act[M,DF] = gelu_q(xb @ w1b^T)
    gemm_bt<true,  bf16_t><<<dim3(DF / 128, M / 128), 256, 0, stream>>>(xb,  w1b, act, M, DF, DM);
    // GEMM2: out[M,DM] = act @ w2b^T
    gemm_bt<false, float ><<<dim3(DM / 128, M / 128), 256, 0, stream>>>(act, w2b, out, M, DM, DF);
}

// Round 2
// 987.439 us; speedup vs baseline: 1.0611x; 1.0611x over previous
//
#include <hip/hip_runtime.h>
#include <cstdint>
#include <cstddef>

// ---------------------------------------------------------------------------
// PiFormerFFN: out = gelu_q(x @ W1^T) @ W2^T     (all GEMMs bf16 MFMA 16x16x32)
// R1 changes vs R0:
//   - fast tanh-gelu epilogue (v_exp_f32 + v_rcp_f32) instead of libm tanhf
//   - XOR LDS swizzle (kc ^ ((row>>1)&3)) -> conflict-free ds_read_b128
//   - GEMM2: XCD-grouped 1-D grid (L%8 = XCD, 8 contiguous row-panels/XCD)
// ---------------------------------------------------------------------------

typedef __bf16 bf16_t;
typedef bf16_t bf16x8 __attribute__((ext_vector_type(8)));
typedef bf16_t bf16x4 __attribute__((ext_vector_type(4)));
typedef float  floatx4 __attribute__((ext_vector_type(4)));

#define AS1 __attribute__((address_space(1)))
#define AS3 __attribute__((address_space(3)))

__device__ __forceinline__ void async_cp16(const void* g, void* l) {
    __builtin_amdgcn_global_load_lds((const AS1 void*)g, (AS3 void*)l, 16, 0, 0);
}

// tanh-approx gelu, fast form:
//   u = k0*(x + k1*x^3);  gelu = 0.5x(1+tanh u) = x * (1 - 1/(1+e^{2u}))
// e^{2u} via __expf (v_exp_f32); reciprocal via v_rcp_f32. ~1e-6 rel error,
// negligible vs the bf16-quantization-driven absmax (~16 vs threshold 53.76).
__device__ __forceinline__ float gelu_fast(float x) {
    const float C0 = 1.5957691216057308f;   // 2*sqrt(2/pi)
    const float C1 = 0.0713548163f;         // C0 * 0.044715
    float u2 = x * fmaf(C1, x * x, C0);     // = 2u
    float e  = __expf(u2);                  // +inf for large x -> rcp = 0 -> x
    float r  = __builtin_amdgcn_rcpf(1.0f + e);
    return x * (1.0f - r);
}

// fp32 -> bf16 (RNE), 4 elems/thread
__global__ __launch_bounds__(256)
void cvt_f32_to_bf16(const float4* __restrict__ in, bf16x4* __restrict__ out, int n4)
{
    int i = blockIdx.x * blockDim.x + threadIdx.x;
    if (i >= n4) return;
    float4 v = in[i];
    bf16x4 o;
    o[0] = (bf16_t)v.x; o[1] = (bf16_t)v.y; o[2] = (bf16_t)v.z; o[3] = (bf16_t)v.w;
    out[i] = o;
}

// C[M,N] = A[M,K] * B[N,K]^T   (both K-contiguous; bf16 in, fp32 acc)
// 128x128 block tile, 4 waves (2x2), each wave 4x4 MFMA 16x16x32 tiles, BK=32.
// LDS layout: row r's 4 16B-chunks stored permuted: chunk kc at slot
// kc ^ ((r>>1)&3). Makes every aligned 8-lane group of ds_read_b128 hit all
// 32 banks exactly once (row stride is 16 banks, so parity covers 16 banks
// and the xor covers the 4 chunk slots within each parity class).
template<bool ACT, typename OutT, bool XCDSWZ>
__global__ __launch_bounds__(256)
void gemm_bt(const bf16_t* __restrict__ A, const bf16_t* __restrict__ B,
             OutT* __restrict__ C, int M, int N, int K, int nbx, int nby)
{
    __shared__ __align__(16) bf16_t As[128 * 32];
    __shared__ __align__(16) bf16_t Bs[128 * 32];

    int bx, by;
    if (XCDSWZ) {
        // L%8 = XCD (dispatch heuristic). Each XCD gets nby/8 contiguous
        // row-panels; within an XCD, x varies fastest -> row-panel L2 reuse.
        const int L   = blockIdx.x;
        const int xcd = L & 7;
        const int j   = L >> 3;
        const int jy  = j / nbx;
        by = xcd * (nby >> 3) + jy;
        bx = j - jy * nbx;
    } else {
        bx = blockIdx.x; by = blockIdx.y;
    }

    const int tid  = threadIdx.x;
    const int lane = tid & 63;
    const int wave = tid >> 6;
    const int wr = (wave >> 1) * 64;
    const int wc = (wave & 1) * 64;
    const int brow = by * 128;
    const int bcol = bx * 128;

    const int lane_m = lane & 15;
    const int lane_q = lane >> 4;
    const int swz    = (lane_m >> 1) & 3;           // row's xor key
    const int ko     = (lane_q ^ swz) * 8;          // element offset of chunk

    floatx4 acc[4][4];
    #pragma unroll
    for (int i = 0; i < 4; ++i)
      #pragma unroll
      for (int j = 0; j < 4; ++j)
        acc[i][j] = (floatx4)0.0f;

    // Staging: LDS chunk c (16B at offset c*16) holds global chunk
    // (row = c>>2, kc = (c&3) ^ ((c>>3)&3)).  Dest = wave base + lane*16
    // (global_load_lds constraint satisfied).
    const int c0 = tid, c1 = tid + 256;
    const int r0 = c0 >> 2, o0 = (((c0 & 3) ^ ((c0 >> 3) & 3)) * 8);
    const int r1 = c1 >> 2, o1 = (((c1 & 3) ^ ((c1 >> 3) & 3)) * 8);

    const bf16_t* Arow0 = A + (size_t)(brow + r0) * K + o0;
    const bf16_t* Arow1 = A + (size_t)(brow + r1) * K + o1;
    const bf16_t* Brow0 = B + (size_t)(bcol + r0) * K + o0;
    const bf16_t* Brow1 = B + (size_t)(bcol + r1) * K + o1;

    for (int kt = 0; kt < K; kt += 32) {
        async_cp16(Arow0 + kt, (char*)As + c0 * 16);
        async_cp16(Arow1 + kt, (char*)As + c1 * 16);
        async_cp16(Brow0 + kt, (char*)Bs + c0 * 16);
        async_cp16(Brow1 + kt, (char*)Bs + c1 * 16);
        __syncthreads();

        bf16x8 af[4], bfr[4];
        #pragma unroll
        for (int i = 0; i < 4; ++i) {
            af[i]  = *(const bf16x8*)(As + (wr + i * 16 + lane_m) * 32 + ko);
            bfr[i] = *(const bf16x8*)(Bs + (wc + i * 16 + lane_m) * 32 + ko);
        }
        #pragma unroll
        for (int mi = 0; mi < 4; ++mi)
          #pragma unroll
          for (int ni = 0; ni < 4; ++ni)
            acc[mi][ni] = __builtin_amdgcn_mfma_f32_16x16x32_bf16(
                af[mi], bfr[ni], acc[mi][ni], 0, 0, 0);
        __syncthreads();
    }

    // Epilogue. C/D layout: col = lane&15, row = (lane>>4)*4 + reg.
    #pragma unroll
    for (int mi = 0; mi < 4; ++mi) {
      #pragma unroll
      for (int ni = 0; ni < 4; ++ni) {
        const int col = bcol + wc + ni * 16 + lane_m;
        #pragma unroll
        for (int r = 0; r < 4; ++r) {
          const int row = brow + wr + mi * 16 + lane_q * 4 + r;
          float h = acc[mi][ni][r];
          if (ACT) {
            float q = rintf(h * 10.0f);           // round half-to-even
            q = fminf(fmaxf(q, -32768.0f), 32767.0f);
            h = gelu_fast(q * 0.1f);
          }
          C[(size_t)row * N + col] = (OutT)h;
        }
      }
    }
}

extern "C" void kernel_launch(void* const* d_in, const int* in_sizes, int n_in,
                              void* d_out, int out_size, void* d_ws, size_t ws_size,
                              hipStream_t stream)
{
    const int M  = 8192;   // BATCH*SEQ
    const int DM = 2048;   // d_model
    const int DF = 8192;   // d_ff

    const float* x  = (const float*)d_in[0];
    const float* W1 = (const float*)d_in[1];
    const float* W2 = (const float*)d_in[2];
    float* out = (float*)d_out;

    bf16_t* xb  = (bf16_t*)d_ws;
    bf16_t* w1b = xb  + (size_t)M  * DM;
    bf16_t* w2b = w1b + (size_t)DF * DM;
    bf16_t* act = w2b + (size_t)DM * DF;

    {
        int n4 = (M * DM) / 4;
        cvt_f32_to_bf16<<<(n4 + 255) / 256, 256, 0, stream>>>((const float4*)x,  (bf16x4*)xb,  n4);
        n4 = (DF * DM) / 4;
        cvt_f32_to_bf16<<<(n4 + 255) / 256, 256, 0, stream>>>((const float4*)W1, (bf16x4*)w1b, n4);
        n4 = (DM * DF) / 4;
        cvt_f32_to_bf16<<<(n4 + 255) / 256, 256, 0, stream>>>((const float4*)W2, (bf16x4*)w2b, n4);
    }

    // GEMM1 + fused quant/gelu: act[M,DF] = gelu_q(xb @ w1b^T)
    gemm_bt<true, bf16_t, false>
        <<<dim3(DF / 128, M / 128), 256, 0, stream>>>(xb, w1b, act, M, DF, DM, 0, 0);
    // GEMM2: out[M,DM] = act @ w2b^T, XCD-grouped block order
    gemm_bt<false, float, true>
        <<<dim3((DM / 128) * (M / 128), 1), 256, 0, stream>>>(act, w2b, out, M, DM, DF, DM / 128, M / 128);
}

// Round 3
// 845.850 us; speedup vs baseline: 1.2387x; 1.1674x over previous
//
#include <hip/hip_runtime.h>
#include <cstdint>
#include <cstddef>

// ---------------------------------------------------------------------------
// PiFormerFFN: out = gelu_q(x @ W1^T) @ W2^T
// R2 changes vs R1:
//   - MFMA shape 16x16x32 -> 32x32x16 (4060 vs 3378 FLOP/cyc pipe ceiling,
//     half the MFMA issue slots). Each wave: 2x2 tiles of 32x32 = 64x64.
//   - LDS store swizzle unchanged (R1 measured 0 conflicts); read addressing
//     adapted: row=lane&31, chunk=(lane>>5)+2*kstep, slot=chunk^((row>>1)&3).
// ---------------------------------------------------------------------------

typedef __bf16 bf16_t;
typedef bf16_t bf16x8 __attribute__((ext_vector_type(8)));
typedef bf16_t bf16x4 __attribute__((ext_vector_type(4)));
typedef float  floatx16 __attribute__((ext_vector_type(16)));

#define AS1 __attribute__((address_space(1)))
#define AS3 __attribute__((address_space(3)))

__device__ __forceinline__ void async_cp16(const void* g, void* l) {
    __builtin_amdgcn_global_load_lds((const AS1 void*)g, (AS3 void*)l, 16, 0, 0);
}

// tanh-approx gelu: gelu = x * (1 - 1/(1+e^{2u})), u = k0*(x + k1*x^3)
__device__ __forceinline__ float gelu_fast(float x) {
    const float C0 = 1.5957691216057308f;   // 2*sqrt(2/pi)
    const float C1 = 0.0713548163f;         // C0 * 0.044715
    float u2 = x * fmaf(C1, x * x, C0);
    float e  = __expf(u2);
    float r  = __builtin_amdgcn_rcpf(1.0f + e);
    return x * (1.0f - r);
}

// fp32 -> bf16 (RNE), 4 elems/thread
__global__ __launch_bounds__(256)
void cvt_f32_to_bf16(const float4* __restrict__ in, bf16x4* __restrict__ out, int n4)
{
    int i = blockIdx.x * blockDim.x + threadIdx.x;
    if (i >= n4) return;
    float4 v = in[i];
    bf16x4 o;
    o[0] = (bf16_t)v.x; o[1] = (bf16_t)v.y; o[2] = (bf16_t)v.z; o[3] = (bf16_t)v.w;
    out[i] = o;
}

// C[M,N] = A[M,K] * B[N,K]^T  (both K-contiguous; bf16 in, fp32 acc)
// 128x128 block tile, 4 waves (2x2), each wave 2x2 MFMA 32x32x16 tiles, BK=32.
template<bool ACT, typename OutT, bool XCDSWZ>
__global__ __launch_bounds__(256)
void gemm_bt(const bf16_t* __restrict__ A, const bf16_t* __restrict__ B,
             OutT* __restrict__ C, int M, int N, int K, int nbx, int nby)
{
    __shared__ __align__(16) bf16_t As[128 * 32];
    __shared__ __align__(16) bf16_t Bs[128 * 32];

    int bx, by;
    if (XCDSWZ) {
        // L%8 = XCD heuristic; each XCD gets nby/8 contiguous row-panels.
        const int L   = blockIdx.x;
        const int xcd = L & 7;
        const int j   = L >> 3;
        const int jy  = j / nbx;
        by = xcd * (nby >> 3) + jy;
        bx = j - jy * nbx;
    } else {
        bx = blockIdx.x; by = blockIdx.y;
    }

    const int tid  = threadIdx.x;
    const int lane = tid & 63;
    const int wave = tid >> 6;
    const int wr = (wave >> 1) * 64;        // wave row offset in 128-tile
    const int wc = (wave & 1) * 64;         // wave col offset
    const int brow = by * 128;
    const int bcol = bx * 128;

    const int l31 = lane & 31;              // MFMA row/col within 32
    const int lh  = lane >> 5;              // half-wave index (k-chunk select)
    const int key = (l31 >> 1) & 3;         // LDS swizzle key for this row

    floatx16 acc[2][2];
    #pragma unroll
    for (int i = 0; i < 2; ++i)
      #pragma unroll
      for (int j = 0; j < 2; ++j)
        acc[i][j] = (floatx16)0.0f;

    // Staging (identical to R1): LDS chunk c (16B at offset c*16) holds
    // global chunk (row = c>>2, kc = (c&3) ^ ((c>>3)&3)).
    const int c0 = tid, c1 = tid + 256;
    const int r0 = c0 >> 2, o0 = (((c0 & 3) ^ ((c0 >> 3) & 3)) * 8);
    const int r1 = c1 >> 2, o1 = (((c1 & 3) ^ ((c1 >> 3) & 3)) * 8);

    const bf16_t* Arow0 = A + (size_t)(brow + r0) * K + o0;
    const bf16_t* Arow1 = A + (size_t)(brow + r1) * K + o1;
    const bf16_t* Brow0 = B + (size_t)(bcol + r0) * K + o0;
    const bf16_t* Brow1 = B + (size_t)(bcol + r1) * K + o1;

    for (int kt = 0; kt < K; kt += 32) {
        async_cp16(Arow0 + kt, (char*)As + c0 * 16);
        async_cp16(Arow1 + kt, (char*)As + c1 * 16);
        async_cp16(Brow0 + kt, (char*)Bs + c0 * 16);
        async_cp16(Brow1 + kt, (char*)Bs + c1 * 16);
        __syncthreads();

        // A frag (32x32x16): lane holds A[row = l31][k = lh*8 .. +8] of the
        // k-step's 16-slice; chunk kc = lh + 2*ks, stored at slot kc^key.
        bf16x8 af[2][2], bfr[2][2];          // [mi][ks] / [ni][ks]
        #pragma unroll
        for (int i = 0; i < 2; ++i) {
          #pragma unroll
          for (int ks = 0; ks < 2; ++ks) {
            const int s = (lh + 2 * ks) ^ key;
            af[i][ks]  = *(const bf16x8*)(As + (wr + i * 32 + l31) * 32 + s * 8);
            bfr[i][ks] = *(const bf16x8*)(Bs + (wc + i * 32 + l31) * 32 + s * 8);
          }
        }
        #pragma unroll
        for (int ks = 0; ks < 2; ++ks)
          #pragma unroll
          for (int mi = 0; mi < 2; ++mi)
            #pragma unroll
            for (int ni = 0; ni < 2; ++ni)
              acc[mi][ni] = __builtin_amdgcn_mfma_f32_32x32x16_bf16(
                  af[mi][ks], bfr[ni][ks], acc[mi][ni], 0, 0, 0);
        __syncthreads();
    }

    // Epilogue. 32x32 C/D layout: col = lane&31,
    // row = (reg&3) + 8*(reg>>2) + 4*(lane>>5).
    #pragma unroll
    for (int mi = 0; mi < 2; ++mi) {
      #pragma unroll
      for (int ni = 0; ni < 2; ++ni) {
        const int col = bcol + wc + ni * 32 + l31;
        #pragma unroll
        for (int r = 0; r < 16; ++r) {
          const int row = brow + wr + mi * 32 + (r & 3) + 8 * (r >> 2) + 4 * lh;
          float h = acc[mi][ni][r];
          if (ACT) {
            float q = rintf(h * 10.0f);          // round half-to-even
            q = fminf(fmaxf(q, -32768.0f), 32767.0f);
            h = gelu_fast(q * 0.1f);
          }
          C[(size_t)row * N + col] = (OutT)h;
        }
      }
    }
}

extern "C" void kernel_launch(void* const* d_in, const int* in_sizes, int n_in,
                              void* d_out, int out_size, void* d_ws, size_t ws_size,
                              hipStream_t stream)
{
    const int M  = 8192;   // BATCH*SEQ
    const int DM = 2048;   // d_model
    const int DF = 8192;   // d_ff

    const float* x  = (const float*)d_in[0];
    const float* W1 = (const float*)d_in[1];
    const float* W2 = (const float*)d_in[2];
    float* out = (float*)d_out;

    bf16_t* xb  = (bf16_t*)d_ws;
    bf16_t* w1b = xb  + (size_t)M  * DM;
    bf16_t* w2b = w1b + (size_t)DF * DM;
    bf16_t* act = w2b + (size_t)DM * DF;

    {
        int n4 = (M * DM) / 4;
        cvt_f32_to_bf16<<<(n4 + 255) / 256, 256, 0, stream>>>((const float4*)x,  (bf16x4*)xb,  n4);
        n4 = (DF * DM) / 4;
        cvt_f32_to_bf16<<<(n4 + 255) / 256, 256, 0, stream>>>((const float4*)W1, (bf16x4*)w1b, n4);
        n4 = (DM * DF) / 4;
        cvt_f32_to_bf16<<<(n4 + 255) / 256, 256, 0, stream>>>((const float4*)W2, (bf16x4*)w2b, n4);
    }

    // GEMM1 + fused quant/gelu: act[M,DF] = gelu_q(xb @ w1b^T)
    gemm_bt<true, bf16_t, false>
        <<<dim3(DF / 128, M / 128), 256, 0, stream>>>(xb, w1b, act, M, DF, DM, 0, 0);
    // GEMM2: out[M,DM] = act @ w2b^T, XCD-grouped block order
    gemm_bt<false, float, true>
        <<<dim3((DM / 128) * (M / 128), 1), 256, 0, stream>>>(act, w2b, out, M, DM, DF, DM / 128, M / 128);
}